// Round 1
// baseline (5793.211 us; speedup 1.0000x reference)
//
#include <hip/hip_runtime.h>
#include <hip/hip_bf16.h>

// Problem constants
#define NB 32
#define LL 1024
#define HH 768
#define RR (NB * LL)          // 32768 rows
#define PE_C (-0.01199263069f) // -ln(10000)/768

// ---------------------------------------------------------------------------
// block-wide reduce of two sums (blockDim.x must be 256)
__device__ __forceinline__ float2 block_reduce2(float a, float b) {
    __shared__ float sa[4], sb[4];
    #pragma unroll
    for (int off = 32; off; off >>= 1) {
        a += __shfl_down(a, off, 64);
        b += __shfl_down(b, off, 64);
    }
    int lane = threadIdx.x & 63, wid = threadIdx.x >> 6;
    __syncthreads();                 // protect sa/sb from a previous call
    if (lane == 0) { sa[wid] = a; sb[wid] = b; }
    __syncthreads();
    a = (sa[0] + sa[1]) + (sa[2] + sa[3]);
    b = (sb[0] + sb[1]) + (sb[2] + sb[3]);
    return make_float2(a, b);
}

// ---------------------------------------------------------------------------
// Per-row mean / rstd over D columns. If ids != nullptr, row r is X[ids[r]].
__global__ __launch_bounds__(256) void row_stats(
    const float* __restrict__ X, const int* __restrict__ ids, int D,
    float* __restrict__ stats)
{
    int r = blockIdx.x;
    const float* row = X + (ids ? (long)ids[r] * D : (long)r * D);
    float s = 0.f, ss = 0.f;
    for (int c = threadIdx.x * 4; c < D; c += 1024) {
        float4 v = *(const float4*)(row + c);
        s  += (v.x + v.y) + (v.z + v.w);
        ss += (v.x * v.x + v.y * v.y) + (v.z * v.z + v.w * v.w);
    }
    float2 t = block_reduce2(s, ss);
    if (threadIdx.x == 0) {
        float mean = t.x / D;
        float var  = fmaxf(t.y / D - mean * mean, 0.f);
        stats[2 * r]     = mean;
        stats[2 * r + 1] = 1.f / sqrtf(var + 1e-12f);
    }
}

// ---------------------------------------------------------------------------
// Y[m][n] = ReLU( sum_k LN1(A)[m][k] * W[n][k] + bias[n] ),  n in [0,768)
// LN1 fused at the A->LDS staging using precomputed stats + g1/b1 columns.
// Tile 64x64, BK=16, thread micro-tile 4x4. grid = (768/64, M/64).
__global__ __launch_bounds__(256) void gemm_ln_relu(
    const float* __restrict__ A, const int* __restrict__ ids, int K,
    const float* __restrict__ W, const float* __restrict__ bias,
    const float* __restrict__ g1, const float* __restrict__ b1,
    const float* __restrict__ stats, float* __restrict__ Y)
{
    __shared__ float As[16][68];   // [k][m], stride 68 floats (16B-aligned rows)
    __shared__ float Bs[16][68];   // [k][n]

    const int tid = threadIdx.x;
    const int n0 = blockIdx.x * 64;
    const int m0 = blockIdx.y * 64;

    const int lr = tid >> 2;          // 0..63 : row within tile (A: m, B: n)
    const int lc = (tid & 3) << 2;    // 0,4,8,12 : k offset

    const int gm = m0 + lr;
    const float* Ap = A + (ids ? (long)ids[gm] * K : (long)gm * K);
    const float* Bp = W + (long)(n0 + lr) * K;
    const float mean = stats[2 * gm];
    const float rstd = stats[2 * gm + 1];

    const int tm = (tid >> 4) << 2;   // 0..60 step 4
    const int tn = (tid & 15) << 2;   // 0..60 step 4

    float acc[4][4] = {};

    for (int k0 = 0; k0 < K; k0 += 16) {
        int k = k0 + lc;
        float4 a4 = make_float4(0.f, 0.f, 0.f, 0.f);
        float4 b4 = make_float4(0.f, 0.f, 0.f, 0.f);
        if (k + 4 <= K) {
            float4 av = *(const float4*)(Ap + k);
            float4 g4 = *(const float4*)(g1 + k);
            float4 bb = *(const float4*)(b1 + k);
            a4.x = (av.x - mean) * rstd * g4.x + bb.x;
            a4.y = (av.y - mean) * rstd * g4.y + bb.y;
            a4.z = (av.z - mean) * rstd * g4.z + bb.z;
            a4.w = (av.w - mean) * rstd * g4.w + bb.w;
            b4 = *(const float4*)(Bp + k);
        }
        As[lc + 0][lr] = a4.x; As[lc + 1][lr] = a4.y;
        As[lc + 2][lr] = a4.z; As[lc + 3][lr] = a4.w;
        Bs[lc + 0][lr] = b4.x; Bs[lc + 1][lr] = b4.y;
        Bs[lc + 2][lr] = b4.z; Bs[lc + 3][lr] = b4.w;
        __syncthreads();
        #pragma unroll
        for (int kk = 0; kk < 16; kk++) {
            float4 a = *(const float4*)&As[kk][tm];
            float4 b = *(const float4*)&Bs[kk][tn];
            acc[0][0] += a.x * b.x; acc[0][1] += a.x * b.y;
            acc[0][2] += a.x * b.z; acc[0][3] += a.x * b.w;
            acc[1][0] += a.y * b.x; acc[1][1] += a.y * b.y;
            acc[1][2] += a.y * b.z; acc[1][3] += a.y * b.w;
            acc[2][0] += a.z * b.x; acc[2][1] += a.z * b.y;
            acc[2][2] += a.z * b.z; acc[2][3] += a.z * b.w;
            acc[3][0] += a.w * b.x; acc[3][1] += a.w * b.y;
            acc[3][2] += a.w * b.z; acc[3][3] += a.w * b.w;
        }
        __syncthreads();
    }

    float4 bias4 = *(const float4*)(bias + n0 + tn);
    #pragma unroll
    for (int i = 0; i < 4; i++) {
        float4 o;
        o.x = fmaxf(acc[i][0] + bias4.x, 0.f);
        o.y = fmaxf(acc[i][1] + bias4.y, 0.f);
        o.z = fmaxf(acc[i][2] + bias4.z, 0.f);
        o.w = fmaxf(acc[i][3] + bias4.w, 0.f);
        *(float4*)(Y + (long)(m0 + tm + i) * HH + n0 + tn) = o;
    }
}

// ---------------------------------------------------------------------------
// out[r] = LN_F( LN2A(yA[r]) + LN2B(yB[r]) + tte[tt[r]] + pe[r % L] )
// One block per row (256 threads x 3 cols). yB may alias outp (row-local,
// all reads precede writes via the reduction barriers).
__global__ __launch_bounds__(256) void combine_final(
    const float* __restrict__ yA, const float* __restrict__ yB,
    const float* __restrict__ gA, const float* __restrict__ bA,
    const float* __restrict__ gB, const float* __restrict__ bB,
    const float* __restrict__ tte, const int* __restrict__ tt,
    const float* __restrict__ gF, const float* __restrict__ bF,
    float* __restrict__ outp)
{
    const int r = blockIdx.x;
    const int l = r & (LL - 1);
    const int tid = threadIdx.x;
    const float* ya = yA + (long)r * HH;
    const float* yb = yB + (long)r * HH;

    float va[3], vb[3], v[3];
    float s = 0.f, ss = 0.f;
    #pragma unroll
    for (int i = 0; i < 3; i++) {
        int c = tid + 256 * i;
        va[i] = ya[c];
        s += va[i]; ss += va[i] * va[i];
    }
    float2 t = block_reduce2(s, ss);
    float uA = t.x / (float)HH;
    float rA = 1.f / sqrtf(fmaxf(t.y / (float)HH - uA * uA, 0.f) + 1e-12f);

    s = 0.f; ss = 0.f;
    #pragma unroll
    for (int i = 0; i < 3; i++) {
        int c = tid + 256 * i;
        vb[i] = yb[c];
        s += vb[i]; ss += vb[i] * vb[i];
    }
    t = block_reduce2(s, ss);
    float uB = t.x / (float)HH;
    float rB = 1.f / sqrtf(fmaxf(t.y / (float)HH - uB * uB, 0.f) + 1e-12f);

    const float* tterow = tte + (long)tt[r] * HH;
    s = 0.f; ss = 0.f;
    #pragma unroll
    for (int i = 0; i < 3; i++) {
        int c = tid + 256 * i;
        int p = c >> 1;
        float ang = (float)l * expf((float)(2 * p) * PE_C);
        float pe = (c & 1) ? cosf(ang) : sinf(ang);
        v[i] = gA[c] * (va[i] - uA) * rA + bA[c]
             + gB[c] * (vb[i] - uB) * rB + bB[c]
             + tterow[c] + pe;
        s += v[i]; ss += v[i] * v[i];
    }
    t = block_reduce2(s, ss);
    float u  = t.x / (float)HH;
    float rs = 1.f / sqrtf(fmaxf(t.y / (float)HH - u * u, 0.f) + 1e-12f);
    #pragma unroll
    for (int i = 0; i < 3; i++) {
        int c = tid + 256 * i;
        outp[(long)r * HH + c] = gF[c] * (v[i] - u) * rs + bF[c];
    }
}

// ---------------------------------------------------------------------------
extern "C" void kernel_launch(void* const* d_in, const int* in_sizes, int n_in,
                              void* d_out, int out_size, void* d_ws, size_t ws_size,
                              hipStream_t stream)
{
    const int*   ids1   = (const int*)  d_in[0];
    const int*   ids2   = (const int*)  d_in[1];
    const float* video  = (const float*)d_in[2];
    const float* region = (const float*)d_in[3];
    const int*   tt1    = (const int*)  d_in[4];
    const int*   tt2    = (const int*)  d_in[5];
    const float* wemb   = (const float*)d_in[6];
    const float* wemb2  = (const float*)d_in[7];
    const float* tte    = (const float*)d_in[8];
    const float* tte2   = (const float*)d_in[9];

    const float* wfc_ln1w  = (const float*)d_in[10];
    const float* wfc_ln1b  = (const float*)d_in[11];
    const float* wfc_W     = (const float*)d_in[12];
    const float* wfc_b     = (const float*)d_in[13];
    const float* wfc_ln2w  = (const float*)d_in[14];
    const float* wfc_ln2b  = (const float*)d_in[15];

    const float* wfc2_ln1w = (const float*)d_in[16];
    const float* wfc2_ln1b = (const float*)d_in[17];
    const float* wfc2_W    = (const float*)d_in[18];
    const float* wfc2_b    = (const float*)d_in[19];
    const float* wfc2_ln2w = (const float*)d_in[20];
    const float* wfc2_ln2b = (const float*)d_in[21];

    const float* vid_ln1w  = (const float*)d_in[22];
    const float* vid_ln1b  = (const float*)d_in[23];
    const float* vid_W     = (const float*)d_in[24];
    const float* vid_b     = (const float*)d_in[25];
    const float* vid_ln2w  = (const float*)d_in[26];
    const float* vid_ln2b  = (const float*)d_in[27];

    const float* reg_ln1w  = (const float*)d_in[28];
    const float* reg_ln1b  = (const float*)d_in[29];
    const float* reg_W     = (const float*)d_in[30];
    const float* reg_b     = (const float*)d_in[31];
    const float* reg_ln2w  = (const float*)d_in[32];
    const float* reg_ln2b  = (const float*)d_in[33];

    const float* ln_w  = (const float*)d_in[34];
    const float* ln_b  = (const float*)d_in[35];
    const float* ln2_w = (const float*)d_in[36];
    const float* ln2_b = (const float*)d_in[37];

    float* out1 = (float*)d_out;                    // e1: 32768x768
    float* out2 = out1 + (long)RR * HH;             // e2

    float* stats = (float*)d_ws;                    // 2*32768 floats
    float* yA    = stats + 2 * RR;                  // 32768x768 floats (~101 MB total ws)

    dim3 gg(HH / 64, RR / 64);   // n-blocks fastest: each A-tile fetched once

    // ---- e1 = LN( wfc(word_emb[ids1]) + vid(video) + tte[tt1] + pe ) ----
    row_stats<<<RR, 256, 0, stream>>>(wemb, ids1, 300, stats);
    gemm_ln_relu<<<gg, 256, 0, stream>>>(wemb, ids1, 300, wfc_W, wfc_b,
                                         wfc_ln1w, wfc_ln1b, stats, yA);
    row_stats<<<RR, 256, 0, stream>>>(video, nullptr, 3072, stats);
    gemm_ln_relu<<<gg, 256, 0, stream>>>(video, nullptr, 3072, vid_W, vid_b,
                                         vid_ln1w, vid_ln1b, stats, out1);
    combine_final<<<RR, 256, 0, stream>>>(yA, out1,
                                          wfc_ln2w, wfc_ln2b, vid_ln2w, vid_ln2b,
                                          tte, tt1, ln_w, ln_b, out1);

    // ---- e2 = LN( wfc2(word_emb2[ids2]) + reg(region) + tte2[tt2] + pe ) ----
    row_stats<<<RR, 256, 0, stream>>>(wemb2, ids2, 300, stats);
    gemm_ln_relu<<<gg, 256, 0, stream>>>(wemb2, ids2, 300, wfc2_W, wfc2_b,
                                         wfc2_ln1w, wfc2_ln1b, stats, yA);
    row_stats<<<RR, 256, 0, stream>>>(region, nullptr, 2048, stats);
    gemm_ln_relu<<<gg, 256, 0, stream>>>(region, nullptr, 2048, reg_W, reg_b,
                                         reg_ln1w, reg_ln1b, stats, out2);
    combine_final<<<RR, 256, 0, stream>>>(yA, out2,
                                          wfc2_ln2w, wfc2_ln2b, reg_ln2w, reg_ln2b,
                                          tte2, tt2, ln2_w, ln2_b, out2);
}